// Round 1
// baseline (628.991 us; speedup 1.0000x reference)
//
#include <hip/hip_runtime.h>
#include <hip/hip_bf16.h>
#include <math.h>

// RG-LRU forward: r,i = sigmoid(x@Wa+ba), sigmoid(x@Wx+bx); a=sigmoid(Lam)
// at = a * 8^{-r}; bt = sqrt(1-at^2)*i*x; y_t = at_t*y_{t-1} + bt_t (scan over T)
// Pipeline: bf16 convert -> fused dual-GEMM (MFMA) w/ epilogue -> 3-phase chunk scan.

#define B_    8
#define T_    4096
#define D_    1024
#define BT_   (B_*T_)

#define BM 128
#define BN 128
#define BK 32

#define TC  256            // scan chunk length
#define NCH (T_/TC)        // 16 chunks per sequence

typedef float  f32x4  __attribute__((ext_vector_type(4)));
typedef __bf16 bf16x8 __attribute__((ext_vector_type(8)));
typedef unsigned short u16;
typedef u16    u16x8  __attribute__((ext_vector_type(8)));

__device__ __forceinline__ u16 f2b(float f){
  union { float f; unsigned u; } c; c.f = f;
  unsigned r = c.u + 0x7fffu + ((c.u >> 16) & 1u);   // round-to-nearest-even
  return (u16)(r >> 16);
}

__device__ __forceinline__ float sigm(float z){
  return 1.0f / (1.0f + __expf(-z));
}

__device__ __forceinline__ void gl_lds16(const void* g, void* l){
  __builtin_amdgcn_global_load_lds(
      (const __attribute__((address_space(1))) void*)g,
      (__attribute__((address_space(3)))       void*)l, 16, 0, 0);
}

// ---------- convert x (fp32 -> bf16), 8 elems/thread ----------
__global__ void cvt_x_k(const float* __restrict__ x, u16* __restrict__ xb){
  size_t i = ((size_t)blockIdx.x * 256 + threadIdx.x) * 8;
  float4 v0 = *reinterpret_cast<const float4*>(x + i);
  float4 v1 = *reinterpret_cast<const float4*>(x + i + 4);
  u16x8 o;
  o[0]=f2b(v0.x); o[1]=f2b(v0.y); o[2]=f2b(v0.z); o[3]=f2b(v0.w);
  o[4]=f2b(v1.x); o[5]=f2b(v1.y); o[6]=f2b(v1.z); o[7]=f2b(v1.w);
  *reinterpret_cast<u16x8*>(xb + i) = o;
}

// ---------- transpose + convert W: wt[h][d] = bf16(w[d][h]), 1024x1024 ----------
__global__ void cvt_wt_k(const float* __restrict__ w, u16* __restrict__ wt){
  __shared__ float t[32][33];
  int tx = threadIdx.x, ty = threadIdx.y;            // block (32,8)
  int h0 = blockIdx.x * 32, d0 = blockIdx.y * 32;
  #pragma unroll
  for (int k = 0; k < 4; ++k){
    int dl = ty + k*8;
    t[dl][tx] = w[(size_t)(d0 + dl)*D_ + h0 + tx];   // coalesced in h
  }
  __syncthreads();
  #pragma unroll
  for (int k = 0; k < 4; ++k){
    int hl = ty + k*8;
    wt[(size_t)(h0 + hl)*D_ + d0 + tx] = f2b(t[tx][hl]);  // coalesced in d
  }
}

// ---------- fused dual GEMM + gate epilogue ----------
// at_out[m][n] = sigmoid(Lam[n]) * 2^{-3*sigmoid((x@Wa)[m][n]+ba[n])}
// bt_out[m][n] = sqrt(1-at^2) * sigmoid((x@Wx)[m][n]+bx[n]) * x[m][n]
__launch_bounds__(256, 2)
__global__ void gemm_atbt_k(const u16* __restrict__ xb,
                            const u16* __restrict__ wat,
                            const u16* __restrict__ wxt,
                            const float* __restrict__ x,
                            const float* __restrict__ ba,
                            const float* __restrict__ bx,
                            const float* __restrict__ lam,
                            float* __restrict__ at_out,
                            float* __restrict__ bt_out)
{
  __shared__ __align__(16) u16 sX [BM*BK];
  __shared__ __align__(16) u16 sWa[BN*BK];
  __shared__ __align__(16) u16 sWx[BN*BK];

  const int tid  = threadIdx.x;
  const int wave = tid >> 6;
  const int lane = tid & 63;
  const int lr   = lane & 15;       // row within 16 (A) / col (B,D)
  const int lkb  = lane >> 4;       // 0..3
  const int lk   = lkb * 8;         // k offset in fragment

  const int m0 = blockIdx.x * BM;   // BT dim
  const int n0 = blockIdx.y * BN;   // H dim
  const int wr = wave >> 1, wc = wave & 1;   // 2x2 wave grid, 64x64 each

  f32x4 accR[4][4] = {};
  f32x4 accI[4][4] = {};

  const u16* xg  = xb  + (size_t)m0 * D_;
  const u16* wag = wat + (size_t)n0 * D_;
  const u16* wxg = wxt + (size_t)n0 * D_;

  for (int k0 = 0; k0 < D_; k0 += BK){
    // stage 3 tiles (128 rows x 32 k, bf16): 2 issues x 256 lanes x 16B each
    #pragma unroll
    for (int i = 0; i < 2; ++i){
      int sb  = i*256 + wave*64;           // wave-uniform slot base
      int s   = sb + lane;                 // per-lane slot
      int row = s >> 2;
      int kb  = (s & 3) * 8;
      size_t go = (size_t)row * D_ + (k0 + kb);
      gl_lds16(xg  + go, (char*)sX  + (size_t)sb*16);
      gl_lds16(wag + go, (char*)sWa + (size_t)sb*16);
      gl_lds16(wxg + go, (char*)sWx + (size_t)sb*16);
    }
    __syncthreads();

    bf16x8 af[4], bfa[4], bfx[4];
    #pragma unroll
    for (int mf = 0; mf < 4; ++mf)
      af[mf] = *reinterpret_cast<const bf16x8*>(&sX[(wr*64 + mf*16 + lr)*BK + lk]);
    #pragma unroll
    for (int nf = 0; nf < 4; ++nf){
      bfa[nf] = *reinterpret_cast<const bf16x8*>(&sWa[(wc*64 + nf*16 + lr)*BK + lk]);
      bfx[nf] = *reinterpret_cast<const bf16x8*>(&sWx[(wc*64 + nf*16 + lr)*BK + lk]);
    }
    #pragma unroll
    for (int mf = 0; mf < 4; ++mf){
      #pragma unroll
      for (int nf = 0; nf < 4; ++nf){
        accR[mf][nf] = __builtin_amdgcn_mfma_f32_16x16x32_bf16(af[mf], bfa[nf], accR[mf][nf], 0, 0, 0);
        accI[mf][nf] = __builtin_amdgcn_mfma_f32_16x16x32_bf16(af[mf], bfx[nf], accI[mf][nf], 0, 0, 0);
      }
    }
    __syncthreads();
  }

  // epilogue: C/D layout col = lane&15, row = (lane>>4)*4 + reg  [m89-verified]
  #pragma unroll
  for (int nf = 0; nf < 4; ++nf){
    int n = n0 + wc*64 + nf*16 + lr;
    float bav = ba[n], bxv = bx[n];
    float aS  = sigm(lam[n]);
    #pragma unroll
    for (int mf = 0; mf < 4; ++mf){
      #pragma unroll
      for (int r = 0; r < 4; ++r){
        int m = m0 + wr*64 + mf*16 + lkb*4 + r;
        float rl  = accR[mf][nf][r] + bav;
        float il  = accI[mf][nf][r] + bxv;
        float rg  = sigm(rl);
        float ig  = sigm(il);
        float atv = aS * exp2f(-3.0f * rg);      // a * 8^{-r}
        size_t o  = (size_t)m * D_ + n;
        float xe  = x[o];
        float btv = sqrtf(fmaxf(0.0f, 1.0f - atv*atv)) * ig * xe;
        at_out[o] = atv;
        bt_out[o] = btv;
      }
    }
  }
}

// ---------- scan phase A: chunk-local inclusive scan (in place on y=bt) ----------
__global__ void scan_a_k(const float* __restrict__ at, float* __restrict__ y,
                         float* __restrict__ aggA, float* __restrict__ aggB)
{
  int h = blockIdx.x * 256 + threadIdx.x;  // D_/256 = 4
  int c = blockIdx.y;                      // NCH
  int b = blockIdx.z;                      // B_
  size_t base = ((size_t)(b*T_ + c*TC)) * D_ + h;
  float run = 0.0f, Ap = 1.0f;
  #pragma unroll 4
  for (int t = 0; t < TC; ++t){
    size_t idx = base + (size_t)t * D_;
    float a  = at[idx];
    float bv = y[idx];
    run = fmaf(a, run, bv);
    Ap *= a;
    y[idx] = run;
  }
  int sidx = (b*NCH + c)*D_ + h;
  aggA[sidx] = Ap;
  aggB[sidx] = run;
}

// ---------- scan phase B: sequential scan over chunk aggregates ----------
__global__ void scan_b_k(const float* __restrict__ aggA, const float* __restrict__ aggB,
                         float* __restrict__ carry)
{
  int i = blockIdx.x * 256 + threadIdx.x;  // 8192 sequences
  int b = i >> 10, h = i & (D_-1);
  float cv = 0.0f;
  for (int c = 0; c < NCH; ++c){
    int sidx = (b*NCH + c)*D_ + h;
    carry[sidx] = cv;
    cv = aggA[sidx]*cv + aggB[sidx];
  }
}

// ---------- scan phase C: apply carry * prefix(at) to chunks 1..NCH-1 ----------
__global__ void scan_c_k(const float* __restrict__ at, const float* __restrict__ carry,
                         float* __restrict__ y)
{
  int h = blockIdx.x * 256 + threadIdx.x;
  int c = blockIdx.y + 1;
  int b = blockIdx.z;
  float cv = carry[(b*NCH + c)*D_ + h];
  if (cv == 0.0f) return;                  // decay^TC underflows for ~all channels
  size_t base = ((size_t)(b*T_ + c*TC)) * D_ + h;
  float pre = 1.0f;
  for (int t = 0; t < TC; ++t){
    size_t idx = base + (size_t)t * D_;
    pre *= at[idx];
    y[idx] += cv * pre;
    if (pre == 0.0f) break;
  }
}

extern "C" void kernel_launch(void* const* d_in, const int* in_sizes, int n_in,
                              void* d_out, int out_size, void* d_ws, size_t ws_size,
                              hipStream_t stream)
{
  const float* x   = (const float*)d_in[0];
  const float* Wa  = (const float*)d_in[1];
  const float* Wx  = (const float*)d_in[2];
  const float* ba  = (const float*)d_in[3];
  const float* bx  = (const float*)d_in[4];
  const float* lam = (const float*)d_in[5];
  float* y = (float*)d_out;

  // workspace layout (bytes):
  //   xb   : bf16 x           67108864
  //   wat  : bf16 Wa^T         2097152
  //   wxt  : bf16 Wx^T         2097152
  //   at   : fp32 at         134217728
  //   aggA/aggB/carry        3x 524288
  // total ~207.1 MB
  char* w = (char*)d_ws;
  u16*   xb    = (u16*)(w);
  u16*   wat   = (u16*)(w + 67108864);
  u16*   wxt   = (u16*)(w + 69206016);
  float* at    = (float*)(w + 71303168);
  float* aggA  = (float*)(w + 205520896);
  float* aggB  = (float*)(w + 206045184);
  float* carry = (float*)(w + 206569472);

  cvt_x_k <<<(BT_*(size_t)D_)/(256*8), 256, 0, stream>>>(x, xb);
  cvt_wt_k<<<dim3(32,32), dim3(32,8), 0, stream>>>(Wa, wat);
  cvt_wt_k<<<dim3(32,32), dim3(32,8), 0, stream>>>(Wx, wxt);

  gemm_atbt_k<<<dim3(BT_/BM, D_/BN), 256, 0, stream>>>(xb, wat, wxt, x, ba, bx, lam, at, y);

  scan_a_k<<<dim3(D_/256, NCH, B_), 256, 0, stream>>>(at, y, aggA, aggB);
  scan_b_k<<<(B_*D_)/256, 256, 0, stream>>>(aggA, aggB, carry);
  scan_c_k<<<dim3(D_/256, NCH-1, B_), 256, 0, stream>>>(at, carry, y);
}

// Round 3
// 592.397 us; speedup vs baseline: 1.0618x; 1.0618x over previous
//
#include <hip/hip_runtime.h>
#include <hip/hip_bf16.h>
#include <math.h>

// RG-LRU forward: r,i = sigmoid(x@Wa+ba), sigmoid(x@Wx+bx); a=sigmoid(Lam)
// at = a * 8^{-r}; bt = sqrt(1-at^2)*i*x; y_t = at_t*y_{t-1} + bt_t (scan over T)
// R2 (resubmit after broker timeout): GEMM LDS k-chunk XOR swizzle (kills 8-way
// ds_read_b128 bank conflict), scan TC 256->128, scan_c early-exit 1e-7.

#define B_    8
#define T_    4096
#define D_    1024
#define BT_   (B_*T_)

#define BM 128
#define BN 128
#define BK 32

#define TC  128            // scan chunk length
#define NCH (T_/TC)        // 32 chunks per sequence

typedef float  f32x4  __attribute__((ext_vector_type(4)));
typedef __bf16 bf16x8 __attribute__((ext_vector_type(8)));
typedef unsigned short u16;
typedef u16    u16x8  __attribute__((ext_vector_type(8)));

__device__ __forceinline__ u16 f2b(float f){
  union { float f; unsigned u; } c; c.f = f;
  unsigned r = c.u + 0x7fffu + ((c.u >> 16) & 1u);   // round-to-nearest-even
  return (u16)(r >> 16);
}

__device__ __forceinline__ float sigm(float z){
  return 1.0f / (1.0f + __expf(-z));
}

__device__ __forceinline__ void gl_lds16(const void* g, void* l){
  __builtin_amdgcn_global_load_lds(
      (const __attribute__((address_space(1))) void*)g,
      (__attribute__((address_space(3)))       void*)l, 16, 0, 0);
}

// ---------- convert x (fp32 -> bf16), 8 elems/thread ----------
__global__ void cvt_x_k(const float* __restrict__ x, u16* __restrict__ xb){
  size_t i = ((size_t)blockIdx.x * 256 + threadIdx.x) * 8;
  float4 v0 = *reinterpret_cast<const float4*>(x + i);
  float4 v1 = *reinterpret_cast<const float4*>(x + i + 4);
  u16x8 o;
  o[0]=f2b(v0.x); o[1]=f2b(v0.y); o[2]=f2b(v0.z); o[3]=f2b(v0.w);
  o[4]=f2b(v1.x); o[5]=f2b(v1.y); o[6]=f2b(v1.z); o[7]=f2b(v1.w);
  *reinterpret_cast<u16x8*>(xb + i) = o;
}

// ---------- transpose + convert W: wt[h][d] = bf16(w[d][h]), 1024x1024 ----------
__global__ void cvt_wt_k(const float* __restrict__ w, u16* __restrict__ wt){
  __shared__ float t[32][33];
  int tx = threadIdx.x, ty = threadIdx.y;            // block (32,8)
  int h0 = blockIdx.x * 32, d0 = blockIdx.y * 32;
  #pragma unroll
  for (int k = 0; k < 4; ++k){
    int dl = ty + k*8;
    t[dl][tx] = w[(size_t)(d0 + dl)*D_ + h0 + tx];   // coalesced in h
  }
  __syncthreads();
  #pragma unroll
  for (int k = 0; k < 4; ++k){
    int hl = ty + k*8;
    wt[(size_t)(h0 + hl)*D_ + d0 + tx] = f2b(t[tx][hl]);  // coalesced in d
  }
}

// ---------- fused dual GEMM + gate epilogue ----------
// LDS layout: slot (row, kbs) at elem row*32 + kbs*8 holds global k-chunk
// kb = kbs ^ ((row>>1)&3). Both-sides involution: staging pre-swizzles the
// GLOBAL source (linear LDS dest, required by global_load_lds), reads XOR the
// same term -> fragment-read bank aliasing drops 8-way -> 2-way (free).
__launch_bounds__(256, 2)
__global__ void gemm_atbt_k(const u16* __restrict__ xb,
                            const u16* __restrict__ wat,
                            const u16* __restrict__ wxt,
                            const float* __restrict__ x,
                            const float* __restrict__ ba,
                            const float* __restrict__ bx,
                            const float* __restrict__ lam,
                            float* __restrict__ at_out,
                            float* __restrict__ bt_out)
{
  __shared__ __align__(16) u16 sX [BM*BK];
  __shared__ __align__(16) u16 sWa[BN*BK];
  __shared__ __align__(16) u16 sWx[BN*BK];

  const int tid  = threadIdx.x;
  const int wave = tid >> 6;
  const int lane = tid & 63;
  const int lr   = lane & 15;       // row within 16 (A) / col (B,D)
  const int lkb  = lane >> 4;       // 0..3
  const int xk   = (lkb ^ ((lr >> 1) & 3)) * 8;   // swizzled k-elem offset

  const int m0 = blockIdx.x * BM;   // BT dim
  const int n0 = blockIdx.y * BN;   // H dim
  const int wr = wave >> 1, wc = wave & 1;   // 2x2 wave grid, 64x64 each

  f32x4 accR[4][4] = {};
  f32x4 accI[4][4] = {};

  const u16* xg  = xb  + (size_t)m0 * D_;
  const u16* wag = wat + (size_t)n0 * D_;
  const u16* wxg = wxt + (size_t)n0 * D_;

  for (int k0 = 0; k0 < D_; k0 += BK){
    // stage 3 tiles (128 rows x 32 k bf16 = 512 slots x 16B each)
    #pragma unroll
    for (int i = 0; i < 2; ++i){
      int sb  = i*256 + wave*64;           // wave-uniform slot base
      int s   = sb + lane;                 // per-lane slot
      int row = s >> 2;
      int kb  = (s & 3) ^ ((row >> 1) & 3);   // pre-swizzled global chunk
      size_t go = (size_t)row * D_ + (k0 + kb*8);
      gl_lds16(xg  + go, (char*)sX  + (size_t)sb*16);
      gl_lds16(wag + go, (char*)sWa + (size_t)sb*16);
      gl_lds16(wxg + go, (char*)sWx + (size_t)sb*16);
    }
    __syncthreads();

    bf16x8 af[4], bfa[4], bfx[4];
    #pragma unroll
    for (int mf = 0; mf < 4; ++mf)
      af[mf] = *reinterpret_cast<const bf16x8*>(&sX[(wr*64 + mf*16 + lr)*BK + xk]);
    #pragma unroll
    for (int nf = 0; nf < 4; ++nf){
      bfa[nf] = *reinterpret_cast<const bf16x8*>(&sWa[(wc*64 + nf*16 + lr)*BK + xk]);
      bfx[nf] = *reinterpret_cast<const bf16x8*>(&sWx[(wc*64 + nf*16 + lr)*BK + xk]);
    }
    #pragma unroll
    for (int mf = 0; mf < 4; ++mf){
      #pragma unroll
      for (int nf = 0; nf < 4; ++nf){
        accR[mf][nf] = __builtin_amdgcn_mfma_f32_16x16x32_bf16(af[mf], bfa[nf], accR[mf][nf], 0, 0, 0);
        accI[mf][nf] = __builtin_amdgcn_mfma_f32_16x16x32_bf16(af[mf], bfx[nf], accI[mf][nf], 0, 0, 0);
      }
    }
    __syncthreads();
  }

  // epilogue: C/D layout col = lane&15, row = (lane>>4)*4 + reg  [m89-verified]
  const int lkb4 = (lane >> 4) * 4;
  #pragma unroll
  for (int nf = 0; nf < 4; ++nf){
    int n = n0 + wc*64 + nf*16 + lr;
    float bav = ba[n], bxv = bx[n];
    float aS  = sigm(lam[n]);
    #pragma unroll
    for (int mf = 0; mf < 4; ++mf){
      #pragma unroll
      for (int r = 0; r < 4; ++r){
        int m = m0 + wr*64 + mf*16 + lkb4 + r;
        float rl  = accR[mf][nf][r] + bav;
        float il  = accI[mf][nf][r] + bxv;
        float rg  = sigm(rl);
        float ig  = sigm(il);
        float atv = aS * exp2f(-3.0f * rg);      // a * 8^{-r}
        size_t o  = (size_t)m * D_ + n;
        float xe  = x[o];
        float btv = sqrtf(fmaxf(0.0f, 1.0f - atv*atv)) * ig * xe;
        at_out[o] = atv;
        bt_out[o] = btv;
      }
    }
  }
}

// ---------- scan phase A: chunk-local inclusive scan (in place on y=bt) ----------
__global__ void scan_a_k(const float* __restrict__ at, float* __restrict__ y,
                         float* __restrict__ aggA, float* __restrict__ aggB)
{
  int h = blockIdx.x * 256 + threadIdx.x;  // D_/256 = 4
  int c = blockIdx.y;                      // NCH
  int b = blockIdx.z;                      // B_
  size_t base = ((size_t)(b*T_ + c*TC)) * D_ + h;
  float run = 0.0f, Ap = 1.0f;
  #pragma unroll 8
  for (int t = 0; t < TC; ++t){
    size_t idx = base + (size_t)t * D_;
    float a  = at[idx];
    float bv = y[idx];
    run = fmaf(a, run, bv);
    Ap *= a;
    y[idx] = run;
  }
  int sidx = (b*NCH + c)*D_ + h;
  aggA[sidx] = Ap;
  aggB[sidx] = run;
}

// ---------- scan phase B: sequential scan over chunk aggregates ----------
__global__ void scan_b_k(const float* __restrict__ aggA, const float* __restrict__ aggB,
                         float* __restrict__ carry)
{
  int i = blockIdx.x * 256 + threadIdx.x;  // 8192 sequences
  int b = i >> 10, h = i & (D_-1);
  float cv = 0.0f;
  for (int c = 0; c < NCH; ++c){
    int sidx = (b*NCH + c)*D_ + h;
    carry[sidx] = cv;
    cv = aggA[sidx]*cv + aggB[sidx];
  }
}

// ---------- scan phase C: y += carry * prefix(at), early-exit on decay ----------
__global__ void scan_c_k(const float* __restrict__ at, const float* __restrict__ carry,
                         float* __restrict__ y)
{
  int h = blockIdx.x * 256 + threadIdx.x;
  int c = blockIdx.y + 1;
  int b = blockIdx.z;
  float cv = carry[(b*NCH + c)*D_ + h];
  size_t base = ((size_t)(b*T_ + c*TC)) * D_ + h;
  float pre = 1.0f;
  for (int t = 0; t < TC; ++t){
    size_t idx = base + (size_t)t * D_;
    pre *= at[idx];
    y[idx] += cv * pre;
    if (pre < 1e-7f) break;   // carry contribution < 1e-7 * O(1): negligible
  }
}

extern "C" void kernel_launch(void* const* d_in, const int* in_sizes, int n_in,
                              void* d_out, int out_size, void* d_ws, size_t ws_size,
                              hipStream_t stream)
{
  const float* x   = (const float*)d_in[0];
  const float* Wa  = (const float*)d_in[1];
  const float* Wx  = (const float*)d_in[2];
  const float* ba  = (const float*)d_in[3];
  const float* bx  = (const float*)d_in[4];
  const float* lam = (const float*)d_in[5];
  float* y = (float*)d_out;

  // workspace layout (bytes):
  //   xb   : bf16 x           67108864   (dead after GEMM -> reused for aggs)
  //   wat  : bf16 Wa^T         2097152
  //   wxt  : bf16 Wx^T         2097152
  //   at   : fp32 at         134217728
  // aggA/aggB/carry (3x 1 MB) alias the dead xb region. total ~205.5 MB
  char* w = (char*)d_ws;
  u16*   xb    = (u16*)(w);
  u16*   wat   = (u16*)(w + 67108864);
  u16*   wxt   = (u16*)(w + 69206016);
  float* at    = (float*)(w + 71303168);
  float* aggA  = (float*)(w);             // aliases xb (dead after GEMM)
  float* aggB  = (float*)(w + 1048576);
  float* carry = (float*)(w + 2097152);

  cvt_x_k <<<(BT_*(size_t)D_)/(256*8), 256, 0, stream>>>(x, xb);
  cvt_wt_k<<<dim3(32,32), dim3(32,8), 0, stream>>>(Wa, wat);
  cvt_wt_k<<<dim3(32,32), dim3(32,8), 0, stream>>>(Wx, wxt);

  gemm_atbt_k<<<dim3(BT_/BM, D_/BN), 256, 0, stream>>>(xb, wat, wxt, x, ba, bx, lam, at, y);

  scan_a_k<<<dim3(D_/256, NCH, B_), 256, 0, stream>>>(at, y, aggA, aggB);
  scan_b_k<<<(B_*D_)/256, 256, 0, stream>>>(aggA, aggB, carry);
  scan_c_k<<<dim3(D_/256, NCH-1, B_), 256, 0, stream>>>(at, carry, y);
}